// Round 16
// baseline (191.613 us; speedup 1.0000x reference)
//
#include <hip/hip_runtime.h>
#include <hip/hip_bf16.h>
#include <math.h>

typedef __attribute__((ext_vector_type(8))) short short8;
typedef __attribute__((ext_vector_type(4))) float floatx4;
typedef __attribute__((ext_vector_type(16))) float floatx16;

#define B_ 8
#define C_ 256
#define N_ 4096
#define LOG2E 1.4426950408889634f
#define XSTRIDE 548   // qkv LDS row stride bytes (137 dw; 137%32=9 -> <=2-way banks r/w)

static __device__ __forceinline__ unsigned short f2bf(float f) {
  union { float f; unsigned int u; } v; v.f = f;
  unsigned int u = v.u;
  u += 0x7FFFu + ((u >> 16) & 1u);   // RNE
  return (unsigned short)(u >> 16);
}
static __device__ __forceinline__ float bf2f(unsigned short h) {
  union { unsigned int u; float f; } v; v.u = ((unsigned int)h) << 16; return v.f;
}
// truncation pack of two positive f32 -> bf16x2 in ONE v_perm_b32 (lo = a, hi = b)
static __device__ __forceinline__ unsigned int pk2(float a, float b) {
  return __builtin_amdgcn_perm(__float_as_uint(b), __float_as_uint(a), 0x07060302u);
}

// ---------------- kernel 0: weight convert + ssq zero ----------------
__global__ void prep_kernel(const float* __restrict__ Wq, const float* __restrict__ Wk,
                            const float* __restrict__ Wv,
                            unsigned short* __restrict__ wqb, unsigned short* __restrict__ wkb,
                            unsigned short* __restrict__ wvb, float* __restrict__ ssq) {
  int t = blockIdx.x * 256 + threadIdx.x;
  if (t < 512) ssq[t] = 0.0f;
  if (t < 8192) { wqb[t] = f2bf(Wq[t]); wkb[t] = f2bf(Wk[t]); }
  int tv = t - 8192;
  if (tv >= 0 && tv < 65536) wvb[tv] = f2bf(Wv[tv]);
}

// ---------------- kernel 1: QKV GEMM, 8-wave pipelined single-pass (r15) ----------------
__launch_bounds__(512, 4)
__global__ void qkv_kernel(const float* __restrict__ x,
                           const unsigned short* __restrict__ wqb,
                           const unsigned short* __restrict__ wkb,
                           const unsigned short* __restrict__ wvb,
                           const float* __restrict__ bq, const float* __restrict__ bk,
                           const float* __restrict__ bv,
                           unsigned short* __restrict__ qbf, unsigned short* __restrict__ kbf,
                           unsigned short* __restrict__ vbf, float* __restrict__ ssq) {
  __shared__ __align__(16) char Xt[64 * XSTRIDE];   // [64 n][256 c bf16 + pad]
  int b = blockIdx.x & 7;
  int nblk = blockIdx.x >> 3;
  int tid = threadIdx.x;
  int w = tid >> 6, lane = tid & 63;
  int r = lane & 15, g = lane >> 4;
  int nh = w & 3, ch = w >> 2;
  int n0 = nblk * 64;

  // ---- stage x tile: [c][n] fp32 -> [n][c] bf16 (transpose via regs), coalesced ----
  {
    int q = tid & 15, cpw = tid >> 4;               // q: float4 col, cpw: c-pair group
    const float* xb = x + ((size_t)b << 20) + n0 + q * 4;
    #pragma unroll
    for (int p = 0; p < 4; ++p) {
      int cp = p * 32 + cpw;                        // c-pair: c = 2cp, 2cp+1
      const float* s0 = xb + ((size_t)(2 * cp) << 12);
      float4 a  = *(const float4*)s0;
      float4 bb = *(const float4*)(s0 + 4096);
      char* dst = Xt + cp * 4;
      *(unsigned int*)(dst + (q * 4 + 0) * XSTRIDE) = pk2(a.x, bb.x);
      *(unsigned int*)(dst + (q * 4 + 1) * XSTRIDE) = pk2(a.y, bb.y);
      *(unsigned int*)(dst + (q * 4 + 2) * XSTRIDE) = pk2(a.z, bb.z);
      *(unsigned int*)(dst + (q * 4 + 3) * XSTRIDE) = pk2(a.w, bb.w);
    }
  }
  __syncthreads();

  // ---- x fragments: col n = n0 + nh*16 + r, k = ks*32 + g*8 + j ----
  short8 xf[8];
  #pragma unroll
  for (int ks = 0; ks < 8; ++ks) {
    const char* src = Xt + (nh * 16 + r) * XSTRIDE + (ks * 32 + g * 8) * 2;
    union { unsigned int u[4]; short8 s8; } t;
    t.u[0] = *(const unsigned int*)(src);
    t.u[1] = *(const unsigned int*)(src + 4);
    t.u[2] = *(const unsigned int*)(src + 8);
    t.u[3] = *(const unsigned int*)(src + 12);
    xf[ks] = t.s8;
  }
  int nw = n0 + nh * 16;
  floatx4 zero = {0.f, 0.f, 0.f, 0.f};
  unsigned short* vt = vbf + (size_t)b * C_ * N_;
  const unsigned short* wqk = ch ? wkb : wqb;
  const float* bias = ch ? bk : bq;
  unsigned short* qkdst = ch ? kbf : qbf;
  int sbase = ch ? 256 : 0;

  const unsigned short* vwb = wvb + (size_t)(ch * 128 + r) * 256 + g * 8;
  const unsigned short* qwb = wqk + (size_t)r * 256 + g * 8;

  short8 wf[2][4];
  #pragma unroll
  for (int j = 0; j < 4; ++j) wf[0][j] = *(const short8*)(vwb + j * 32);

  #pragma unroll
  for (int t = 0; t < 10; ++t) {
    const unsigned short* curb = (t < 8) ? (vwb + t * 4096) : (qwb + (t - 8) * 4096);
    const unsigned short* nxtb = (t < 7) ? (vwb + (t + 1) * 4096)
                                         : ((t < 9) ? (qwb + (t - 7) * 4096) : curb);
    floatx4 acc = zero;
    #pragma unroll
    for (int j = 0; j < 4; ++j) wf[1][j] = *(const short8*)(curb + (4 + j) * 32);
    #pragma unroll
    for (int j = 0; j < 4; ++j)
      acc = __builtin_amdgcn_mfma_f32_16x16x32_bf16(wf[0][j], xf[j], acc, 0, 0, 0);
    #pragma unroll
    for (int j = 0; j < 4; ++j) wf[0][j] = *(const short8*)(nxtb + j * 32);
    #pragma unroll
    for (int j = 0; j < 4; ++j)
      acc = __builtin_amdgcn_mfma_f32_16x16x32_bf16(wf[1][j], xf[4 + j], acc, 0, 0, 0);

    if (t < 8) {                                    // V tile: tiled-layout stores
      int otile = ch * 8 + t;
      #pragma unroll
      for (int rr = 0; rr < 4; ++rr) {
        int oc = otile * 16 + g * 4 + rr;
        int n = nw + r;
        vt[(size_t)(n >> 3) * 2048 + oc * 8 + (n & 7)] = f2bf(acc[rr] + bv[oc]);
      }
    } else {                                        // Q (ch=0) / K (ch=1) tile
      #pragma unroll
      for (int rr = 0; rr < 4; ++rr) {
        int oc = (t - 8) * 16 + g * 4 + rr;
        float val = acc[rr] + bias[oc];
        qkdst[(size_t)(b * N_ + nw + r) * 32 + oc] = f2bf(val);
        float s = val * val;
        s += __shfl_xor(s, 1);
        s += __shfl_xor(s, 2);
        s += __shfl_xor(s, 4);
        s += __shfl_xor(s, 8);
        if (r == 0) atomicAdd(&ssq[sbase + b * 32 + oc], s);
      }
    }
  }
}

// ---------------- kernel 2: FAT-WAVE barrier-free attention ----------------
// Grid 256 = 1 block/CU. Block 256 thr = 4 waves = ms(2: 64-m half) x cvh(2: 128-ch half).
// Wave owns 64 m (2 m-tiles) x 128 ch: V fragments amortize over 2 m-tiles -> per-CU V
// read traffic 32 KB/tile (r14/15 was 64 KB = the L1 wall). 1 wave/SIMD, 512-VGPR regime
// (launch_bounds min-waves=1): acc 128 + V dbuf 64 + K/Q ~32 regs, no spill expected.
// Zero LDS, zero barriers; K/V register double-buffered one full tile ahead.
__launch_bounds__(256, 1)
__global__ void attn_kernel(const unsigned short* __restrict__ qbf,
                            const unsigned short* __restrict__ kbf,
                            const unsigned short* __restrict__ vbf,
                            const float* __restrict__ ssq, const float* __restrict__ temp,
                            const float* __restrict__ x, const float* __restrict__ gamma,
                            float* __restrict__ out) {
  int b = blockIdx.x & 7, mblk = blockIdx.x >> 3;       // mblk in [0,32)
  int tid = threadIdx.x;
  int w = tid >> 6, lane = tid & 63, c = lane & 31, h = lane >> 5;
  int ms = w >> 1, cvh = w & 1;                         // ms: 64-m half, cvh: 128-ch half
  const unsigned short* qb = qbf + (size_t)b * N_ * 32;
  const unsigned short* kb = kbf + (size_t)b * N_ * 32;
  const unsigned short* vt = vbf + (size_t)b * C_ * N_;
  int mrow0 = mblk * 128 + ms * 64 + c;                 // m-tile 0 row; m-tile 1 = +32
  int tdiag0 = mblk * 4 + ms * 2;                       // diag tiles: tdiag0 (mt0), +1 (mt1)

  // ---- Q fragments (2 m-tiles) with folded scale: invt*log2e/(||q_c||*||k_c||) ----
  float invt = LOG2E / (temp[0] + 1e-6f);
  float qsc[16];
  #pragma unroll
  for (int j = 0; j < 8; ++j) {
    int ch0 = h * 8 + j, ch1 = 16 + h * 8 + j;
    qsc[j]     = invt * rsqrtf(fmaxf(ssq[b * 32 + ch0] * ssq[256 + b * 32 + ch0], 1e-24f));
    qsc[8 + j] = invt * rsqrtf(fmaxf(ssq[b * 32 + ch1] * ssq[256 + b * 32 + ch1], 1e-24f));
  }
  short8 qf[2][2];
  #pragma unroll
  for (int mt = 0; mt < 2; ++mt) {
    int mr = mrow0 + mt * 32;
    short8 a = *(const short8*)&qb[mr * 32 + h * 8];
    short8 bq8 = *(const short8*)&qb[mr * 32 + 16 + h * 8];
    #pragma unroll
    for (int j = 0; j < 8; ++j) {
      ((unsigned short*)&qf[mt][0])[j] = f2bf(bf2f(((const unsigned short*)&a)[j]) * qsc[j]);
      ((unsigned short*)&qf[mt][1])[j] = f2bf(bf2f(((const unsigned short*)&bq8)[j]) * qsc[8 + j]);
    }
  }

  // K fragment pointer: row n = t*32 + c, channels h*8 / 16+h*8; +1024 elems/tile
  const unsigned short* kp = kb + (size_t)c * 32 + h * 8;
  // V fragment pointers (tiled layout): +8192 elems/tile; cvt*256 elem imm offsets
  const unsigned short* vp0 = vt + h * 2048 + (cvh * 128 + c) * 8;
  const unsigned short* vp1 = vp0 + 4096;

  floatx16 minit;                                        // C-init = -2*log2e (softmax shift)
  #pragma unroll
  for (int i = 0; i < 16; ++i) minit[i] = -2.0f * LOG2E;
  floatx16 zero16 = {0,0,0,0,0,0,0,0,0,0,0,0,0,0,0,0};
  floatx16 acc[2][4];                                    // [mt][cvt] D[cv 32][m 32]
  #pragma unroll
  for (int mt = 0; mt < 2; ++mt)
    #pragma unroll
    for (int cvt = 0; cvt < 4; ++cvt) acc[mt][cvt] = zero16;
  float Lp0 = 0.0f, Lp1 = 0.0f;
  short8 kfA[2], kfB[2], afA[8], afB[8];

  // ---- prologue: load K(0), V(0) ----
  kfA[0] = *(const short8*)kp;
  kfA[1] = *(const short8*)(kp + 16);
  kp += 1024;
  #pragma unroll
  for (int k = 0; k < 8; ++k)
    afA[k] = *(const short8*)(((k >> 2) ? vp1 : vp0) + (k & 3) * 256);
  vp0 += 8192; vp1 += 8192;

  auto body = [&](int t, short8 (&kfC)[2], short8 (&kfN)[2],
                  short8 (&afC)[8], short8 (&afN)[8]) {
    if (t + 1 < 128) {                                  // issue K(t+1), V(t+1)
      kfN[0] = *(const short8*)kp;
      kfN[1] = *(const short8*)(kp + 16);
      kp += 1024;
      #pragma unroll
      for (int k = 0; k < 8; ++k)
        afN[k] = *(const short8*)(((k >> 2) ? vp1 : vp0) + (k & 3) * 256);
      vp0 += 8192; vp1 += 8192;
    }
    #pragma unroll
    for (int mt = 0; mt < 2; ++mt) {
      floatx16 s = __builtin_amdgcn_mfma_f32_32x32x16_bf16(kfC[0], qf[mt][0], minit, 0, 0, 0);
      s = __builtin_amdgcn_mfma_f32_32x32x16_bf16(kfC[1], qf[mt][1], s, 0, 0, 0);
      if (t == tdiag0 + mt && ((c >> 2) & 1) == h)      // +I where global n == m
        s[(c & 3) | ((c >> 3) << 2)] += LOG2E;
      float p[16];
      float ls = 0.0f;
      #pragma unroll
      for (int i = 0; i < 16; ++i) {
        p[i] = __builtin_amdgcn_exp2f(s[i]);
        ls += p[i];
      }
      if (mt == 0) Lp0 += ls; else Lp1 += ls;
      #pragma unroll
      for (int t16 = 0; t16 < 2; ++t16) {
        unsigned int q0 = pk2(p[8*t16+0], p[8*t16+1]);
        unsigned int q1 = pk2(p[8*t16+2], p[8*t16+3]);
        unsigned int q2 = pk2(p[8*t16+4], p[8*t16+5]);
        unsigned int q3 = pk2(p[8*t16+6], p[8*t16+7]);
        // swap(vdst,vsrc): vdst[0:31] <-> vsrc[32:63]
        asm volatile("v_permlane32_swap_b32 %0, %1" : "+v"(q2), "+v"(q0));
        asm volatile("v_permlane32_swap_b32 %0, %1" : "+v"(q3), "+v"(q1));
        union { unsigned int u[4]; short8 s8; } bf;
        bf.u[0] = q0; bf.u[1] = q1; bf.u[2] = q2; bf.u[3] = q3;
        #pragma unroll
        for (int cvt = 0; cvt < 4; ++cvt)
          acc[mt][cvt] = __builtin_amdgcn_mfma_f32_32x32x16_bf16(afC[t16 * 4 + cvt], bf.s8, acc[mt][cvt], 0, 0, 0);
      }
    }
  };

  #pragma unroll 1
  for (int t = 0; t < 128; t += 2) {
    body(t, kfA, kfB, afA, afB);
    body(t + 1, kfB, kfA, afB, afA);
  }

  // denominators: lane holds half the n-sum for column m; partner (lane^32) has the rest
  Lp0 += __shfl_xor(Lp0, 32);
  Lp1 += __shfl_xor(Lp1, 32);
  float linv[2] = {1.0f / Lp0, 1.0f / Lp1};
  float gam = gamma[0];
  #pragma unroll
  for (int mt = 0; mt < 2; ++mt)
    #pragma unroll
    for (int cvt = 0; cvt < 4; ++cvt)
      #pragma unroll
      for (int i = 0; i < 16; ++i) {
        int cv = cvh * 128 + cvt * 32 + (i & 3) + 8 * (i >> 2) + 4 * h;
        size_t idx = ((size_t)(b * C_ + cv) << 12) + mrow0 + mt * 32;
        out[idx] = gam * acc[mt][cvt][i] * linv[mt] + x[idx];
      }
}

extern "C" void kernel_launch(void* const* d_in, const int* in_sizes, int n_in,
                              void* d_out, int out_size, void* d_ws, size_t ws_size,
                              hipStream_t stream) {
  (void)in_sizes; (void)n_in; (void)out_size; (void)ws_size;
  const float* x    = (const float*)d_in[0];
  const float* Wq   = (const float*)d_in[1];
  const float* bq   = (const float*)d_in[2];
  const float* Wk   = (const float*)d_in[3];
  const float* bk   = (const float*)d_in[4];
  const float* Wv   = (const float*)d_in[5];
  const float* bv   = (const float*)d_in[6];
  const float* gam  = (const float*)d_in[7];
  const float* temp = (const float*)d_in[8];
  float* out = (float*)d_out;

  char* ws = (char*)d_ws;
  unsigned short* vbf = (unsigned short*)ws;                       // 16 MB (tiled layout)
  unsigned short* qbf = (unsigned short*)(ws + (16u << 20));       // 2 MB
  unsigned short* kbf = (unsigned short*)(ws + (18u << 20));       // 2 MB
  unsigned short* wqb = (unsigned short*)(ws + (20u << 20));       // 16 KB
  unsigned short* wkb = wqb + 8192;                                // 16 KB
  unsigned short* wvb = wkb + 8192;                                // 128 KB
  float* ssq = (float*)(wvb + 65536);                              // 2 KB

  prep_kernel<<<dim3(288), dim3(256), 0, stream>>>(Wq, Wk, Wv, wqb, wkb, wvb, ssq);
  qkv_kernel<<<dim3(512), dim3(512), 0, stream>>>(x, wqb, wkb, wvb, bq, bk, bv, qbf, kbf, vbf, ssq);
  attn_kernel<<<dim3(256), dim3(256), 0, stream>>>(qbf, kbf, vbf, ssq, temp, x, gam, out);
}

// Round 17
// 158.681 us; speedup vs baseline: 1.2075x; 1.2075x over previous
//
#include <hip/hip_runtime.h>
#include <hip/hip_bf16.h>
#include <math.h>

typedef __attribute__((ext_vector_type(8))) short short8;
typedef __attribute__((ext_vector_type(4))) float floatx4;
typedef __attribute__((ext_vector_type(16))) float floatx16;

#define B_ 8
#define C_ 256
#define N_ 4096
#define LOG2E 1.4426950408889634f
#define XSTRIDE 548   // qkv LDS row stride bytes (137 dw; 137%32=9 -> <=2-way banks r/w)

static __device__ __forceinline__ unsigned short f2bf(float f) {
  union { float f; unsigned int u; } v; v.f = f;
  unsigned int u = v.u;
  u += 0x7FFFu + ((u >> 16) & 1u);   // RNE
  return (unsigned short)(u >> 16);
}
static __device__ __forceinline__ float bf2f(unsigned short h) {
  union { unsigned int u; float f; } v; v.u = ((unsigned int)h) << 16; return v.f;
}
// truncation pack of two positive f32 -> bf16x2 in ONE v_perm_b32 (lo = a, hi = b)
static __device__ __forceinline__ unsigned int pk2(float a, float b) {
  return __builtin_amdgcn_perm(__float_as_uint(b), __float_as_uint(a), 0x07060302u);
}

// ---------------- kernel 0: weight convert + ssq zero ----------------
__global__ void prep_kernel(const float* __restrict__ Wq, const float* __restrict__ Wk,
                            const float* __restrict__ Wv,
                            unsigned short* __restrict__ wqb, unsigned short* __restrict__ wkb,
                            unsigned short* __restrict__ wvb, float* __restrict__ ssq) {
  int t = blockIdx.x * 256 + threadIdx.x;
  if (t < 512) ssq[t] = 0.0f;
  if (t < 8192) { wqb[t] = f2bf(Wq[t]); wkb[t] = f2bf(Wk[t]); }
  int tv = t - 8192;
  if (tv >= 0 && tv < 65536) wvb[tv] = f2bf(Wv[tv]);
}

// ---------------- kernel 1: QKV GEMM, 8-wave pipelined single-pass ----------------
// V now written as FP8 e4m3 in a tiled layout: byte off(n,cv) =
// (n>>5)*8192 + cv*32 + ((n>>3)&1)*16 + ((n>>4)&1)*8 + (n&7)
// -> attn wave reads one contiguous 1KB block per (cvt) load (16B/lane, both k-halves).
__launch_bounds__(512, 4)
__global__ void qkv_kernel(const float* __restrict__ x,
                           const unsigned short* __restrict__ wqb,
                           const unsigned short* __restrict__ wkb,
                           const unsigned short* __restrict__ wvb,
                           const float* __restrict__ bq, const float* __restrict__ bk,
                           const float* __restrict__ bv,
                           unsigned short* __restrict__ qbf, unsigned short* __restrict__ kbf,
                           unsigned char* __restrict__ vbf, float* __restrict__ ssq) {
  __shared__ __align__(16) char Xt[64 * XSTRIDE];   // [64 n][256 c bf16 + pad]
  int b = blockIdx.x & 7;
  int nblk = blockIdx.x >> 3;
  int tid = threadIdx.x;
  int w = tid >> 6, lane = tid & 63;
  int r = lane & 15, g = lane >> 4;
  int nh = w & 3, ch = w >> 2;
  int n0 = nblk * 64;

  // ---- stage x tile: [c][n] fp32 -> [n][c] bf16 (transpose via regs), coalesced ----
  {
    int q = tid & 15, cpw = tid >> 4;               // q: float4 col, cpw: c-pair group
    const float* xb = x + ((size_t)b << 20) + n0 + q * 4;
    #pragma unroll
    for (int p = 0; p < 4; ++p) {
      int cp = p * 32 + cpw;                        // c-pair: c = 2cp, 2cp+1
      const float* s0 = xb + ((size_t)(2 * cp) << 12);
      float4 a  = *(const float4*)s0;
      float4 bb = *(const float4*)(s0 + 4096);
      char* dst = Xt + cp * 4;
      *(unsigned int*)(dst + (q * 4 + 0) * XSTRIDE) = pk2(a.x, bb.x);
      *(unsigned int*)(dst + (q * 4 + 1) * XSTRIDE) = pk2(a.y, bb.y);
      *(unsigned int*)(dst + (q * 4 + 2) * XSTRIDE) = pk2(a.z, bb.z);
      *(unsigned int*)(dst + (q * 4 + 3) * XSTRIDE) = pk2(a.w, bb.w);
    }
  }
  __syncthreads();

  // ---- x fragments: col n = n0 + nh*16 + r, k = ks*32 + g*8 + j ----
  short8 xf[8];
  #pragma unroll
  for (int ks = 0; ks < 8; ++ks) {
    const char* src = Xt + (nh * 16 + r) * XSTRIDE + (ks * 32 + g * 8) * 2;
    union { unsigned int u[4]; short8 s8; } t;
    t.u[0] = *(const unsigned int*)(src);
    t.u[1] = *(const unsigned int*)(src + 4);
    t.u[2] = *(const unsigned int*)(src + 8);
    t.u[3] = *(const unsigned int*)(src + 12);
    xf[ks] = t.s8;
  }
  int nw = n0 + nh * 16;
  floatx4 zero = {0.f, 0.f, 0.f, 0.f};
  unsigned char* vt = vbf + (size_t)b * C_ * N_;
  const unsigned short* wqk = ch ? wkb : wqb;
  const float* bias = ch ? bk : bq;
  unsigned short* qkdst = ch ? kbf : qbf;
  int sbase = ch ? 256 : 0;

  const unsigned short* vwb = wvb + (size_t)(ch * 128 + r) * 256 + g * 8;
  const unsigned short* qwb = wqk + (size_t)r * 256 + g * 8;

  short8 wf[2][4];
  #pragma unroll
  for (int j = 0; j < 4; ++j) wf[0][j] = *(const short8*)(vwb + j * 32);

  // per-lane V store base (n fixed): fp8 tiled layout
  int n = nw + r;
  size_t vsb = (size_t)(n >> 5) * 8192 + ((n >> 3) & 1) * 16 + ((n >> 4) & 1) * 8 + (n & 7);

  #pragma unroll
  for (int t = 0; t < 10; ++t) {
    const unsigned short* curb = (t < 8) ? (vwb + t * 4096) : (qwb + (t - 8) * 4096);
    const unsigned short* nxtb = (t < 7) ? (vwb + (t + 1) * 4096)
                                         : ((t < 9) ? (qwb + (t - 7) * 4096) : curb);
    floatx4 acc = zero;
    #pragma unroll
    for (int j = 0; j < 4; ++j) wf[1][j] = *(const short8*)(curb + (4 + j) * 32);
    #pragma unroll
    for (int j = 0; j < 4; ++j)
      acc = __builtin_amdgcn_mfma_f32_16x16x32_bf16(wf[0][j], xf[j], acc, 0, 0, 0);
    #pragma unroll
    for (int j = 0; j < 4; ++j) wf[0][j] = *(const short8*)(nxtb + j * 32);
    #pragma unroll
    for (int j = 0; j < 4; ++j)
      acc = __builtin_amdgcn_mfma_f32_16x16x32_bf16(wf[1][j], xf[4 + j], acc, 0, 0, 0);

    if (t < 8) {                                    // V tile: fp8 tiled-layout stores
      int otile = ch * 8 + t;
      #pragma unroll
      for (int rr = 0; rr < 4; ++rr) {
        int oc = otile * 16 + g * 4 + rr;
        float val = acc[rr] + bv[oc];
        int pk8 = __builtin_amdgcn_cvt_pk_fp8_f32(val, val, 0, false);
        vt[vsb + (size_t)oc * 32] = (unsigned char)(pk8 & 0xFF);
      }
    } else {                                        // Q (ch=0) / K (ch=1) tile
      #pragma unroll
      for (int rr = 0; rr < 4; ++rr) {
        int oc = (t - 8) * 16 + g * 4 + rr;
        float val = acc[rr] + bias[oc];
        qkdst[(size_t)(b * N_ + nw + r) * 32 + oc] = f2bf(val);
        float s = val * val;
        s += __shfl_xor(s, 1);
        s += __shfl_xor(s, 2);
        s += __shfl_xor(s, 4);
        s += __shfl_xor(s, 8);
        if (r == 0) atomicAdd(&ssq[sbase + b * 32 + oc], s);
      }
    }
  }
}

// ---------------- kernel 2: barrier-free attention, FP8 V & P ----------------
// r14 thin structure (4 waves = ms(2) x cvh(2), m=64, grid 512, 2 blocks/CU) with the PV
// path in fp8 e4m3: V fragments 16B/lane/tile (one load covers both K=16 halves), P packed
// via v_cvt_pk_fp8_f32 + one permlane32_swap per k-half. Per-CU L1 traffic 80->48 KB/tile.
// QK stays bf16.
__launch_bounds__(256, 2)
__global__ void attn_kernel(const unsigned short* __restrict__ qbf,
                            const unsigned short* __restrict__ kbf,
                            const unsigned char* __restrict__ vbf,
                            const float* __restrict__ ssq, const float* __restrict__ temp,
                            const float* __restrict__ x, const float* __restrict__ gamma,
                            float* __restrict__ out) {
  int b = blockIdx.x & 7, mblk = blockIdx.x >> 3;       // mblk in [0,64)
  int tid = threadIdx.x;
  int w = tid >> 6, lane = tid & 63, c = lane & 31, h = lane >> 5;
  int ms = w & 1, cvh = w >> 1;                         // 4 waves: ms(2) x cvh(2)
  const unsigned short* qb = qbf + (size_t)b * N_ * 32;
  const unsigned short* kb = kbf + (size_t)b * N_ * 32;
  const unsigned char* vt = vbf + (size_t)b * C_ * N_;
  int mrow = mblk * 64 + ms * 32 + c;                   // this lane's global m (column)
  int tdiag = mblk * 2 + ms;

  // ---- Q fragments with folded per-channel scale: invt*log2e/(||q_c||*||k_c||) ----
  float invt = LOG2E / (temp[0] + 1e-6f);
  short8 q0r = *(const short8*)&qb[mrow * 32 + h * 8];
  short8 q1r = *(const short8*)&qb[mrow * 32 + 16 + h * 8];
  short8 qf0, qf1;
  #pragma unroll
  for (int j = 0; j < 8; ++j) {
    int ch0 = h * 8 + j, ch1 = 16 + h * 8 + j;
    float s0 = invt * rsqrtf(fmaxf(ssq[b * 32 + ch0] * ssq[256 + b * 32 + ch0], 1e-24f));
    float s1 = invt * rsqrtf(fmaxf(ssq[b * 32 + ch1] * ssq[256 + b * 32 + ch1], 1e-24f));
    ((unsigned short*)&qf0)[j] = f2bf(bf2f(((const unsigned short*)&q0r)[j]) * s0);
    ((unsigned short*)&qf1)[j] = f2bf(bf2f(((const unsigned short*)&q1r)[j]) * s1);
  }

  // K fragment pointer: row n = t*32 + c, channels h*8 / 16+h*8; +1024 elems/tile
  const unsigned short* kp = kb + (size_t)c * 32 + h * 8;
  // V fragment pointer (fp8 tiled): lane reads 16B at (cv)*32 + h*16, +8192 B/tile,
  // cvt imm offset cvt*1024
  const unsigned char* vp = vt + (size_t)(cvh * 128 + c) * 32 + h * 16;

  floatx16 minit;                                        // C-init = -2*log2e (softmax shift)
  #pragma unroll
  for (int i = 0; i < 16; ++i) minit[i] = -2.0f * LOG2E;
  floatx16 zero16 = {0,0,0,0,0,0,0,0,0,0,0,0,0,0,0,0};
  floatx16 acc[4] = {zero16, zero16, zero16, zero16};    // [cvt] D[cv 32][m 32]
  float Lp = 0.0f;
  short8 kfA[2], kfB[2], afA[4], afB[4];

  // ---- prologue: load K(0), V(0) ----
  kfA[0] = *(const short8*)kp;
  kfA[1] = *(const short8*)(kp + 16);
  kp += 1024;
  #pragma unroll
  for (int cvt = 0; cvt < 4; ++cvt)
    afA[cvt] = *(const short8*)(vp + cvt * 1024);
  vp += 8192;

  auto body = [&](int t, short8 (&kfC)[2], short8 (&kfN)[2],
                  short8 (&afC)[4], short8 (&afN)[4]) {
    if (t + 1 < 128) {                                  // issue K(t+1), V(t+1)
      kfN[0] = *(const short8*)kp;
      kfN[1] = *(const short8*)(kp + 16);
      kp += 1024;
      #pragma unroll
      for (int cvt = 0; cvt < 4; ++cvt)
        afN[cvt] = *(const short8*)(vp + cvt * 1024);
      vp += 8192;
    }
    // QK^T (bf16, K loaded a full tile ago)
    floatx16 s = __builtin_amdgcn_mfma_f32_32x32x16_bf16(kfC[0], qf0, minit, 0, 0, 0);
    s = __builtin_amdgcn_mfma_f32_32x32x16_bf16(kfC[1], qf1, s, 0, 0, 0);
    if (t == tdiag && ((c >> 2) & 1) == h)              // +I where global n == m
      s[(c & 3) | ((c >> 3) << 2)] += LOG2E;
    float p[16];
    #pragma unroll
    for (int i = 0; i < 16; ++i) p[i] = __builtin_amdgcn_exp2f(s[i]);
    // tree-sum for L
    Lp += (((p[0] + p[1]) + (p[2] + p[3])) + ((p[4] + p[5]) + (p[6] + p[7])))
        + (((p[8] + p[9]) + (p[10] + p[11])) + ((p[12] + p[13]) + (p[14] + p[15])));
    #pragma unroll
    for (int t16 = 0; t16 < 2; ++t16) {
      // own rows (rel t16*16): d0 = rows 4h+0..3, d1 = rows 8+4h..11+4h (fp8 x4 each)
      int d0 = __builtin_amdgcn_cvt_pk_fp8_f32(p[8*t16+0], p[8*t16+1], 0, false);
      d0 = __builtin_amdgcn_cvt_pk_fp8_f32(p[8*t16+2], p[8*t16+3], d0, true);
      int d1 = __builtin_amdgcn_cvt_pk_fp8_f32(p[8*t16+4], p[8*t16+5], 0, false);
      d1 = __builtin_amdgcn_cvt_pk_fp8_f32(p[8*t16+6], p[8*t16+7], d1, true);
      // swap(vdst=d1, vsrc=d0): lo lanes d1 <- partner d0 (rows 4-7);
      // hi lanes d0 <- partner d1 (rows 8-11). Result B = [d0, d1] = k 0..7 per lane.
      asm volatile("v_permlane32_swap_b32 %0, %1" : "+v"(d1), "+v"(d0));
      long bl = (long)(((unsigned long long)(unsigned)d1 << 32) | (unsigned)d0);
      #pragma unroll
      for (int cvt = 0; cvt < 4; ++cvt) {
        union { short8 s8; long l[2]; } u; u.s8 = afC[cvt];
        acc[cvt] = __builtin_amdgcn_mfma_f32_32x32x16_fp8_fp8(u.l[t16], bl, acc[cvt], 0, 0, 0);
      }
    }
  };

  #pragma unroll 1
  for (int t = 0; t < 128; t += 2) {
    body(t, kfA, kfB, afA, afB);
    body(t + 1, kfB, kfA, afB, afA);
  }

  // denominator: lane holds half the n-sum for column m; partner (lane^32) has the rest
  Lp += __shfl_xor(Lp, 32);
  float linv = 1.0f / Lp;
  float gam = gamma[0];
  #pragma unroll
  for (int cvt = 0; cvt < 4; ++cvt)
    #pragma unroll
    for (int i = 0; i < 16; ++i) {
      int cv = cvh * 128 + cvt * 32 + (i & 3) + 8 * (i >> 2) + 4 * h;
      size_t idx = ((size_t)(b * C_ + cv) << 12) + mrow;
      out[idx] = gam * acc[cvt][i] * linv + x[idx];
    }
}

extern "C" void kernel_launch(void* const* d_in, const int* in_sizes, int n_in,
                              void* d_out, int out_size, void* d_ws, size_t ws_size,
                              hipStream_t stream) {
  (void)in_sizes; (void)n_in; (void)out_size; (void)ws_size;
  const float* x    = (const float*)d_in[0];
  const float* Wq   = (const float*)d_in[1];
  const float* bq   = (const float*)d_in[2];
  const float* Wk   = (const float*)d_in[3];
  const float* bk   = (const float*)d_in[4];
  const float* Wv   = (const float*)d_in[5];
  const float* bv   = (const float*)d_in[6];
  const float* gam  = (const float*)d_in[7];
  const float* temp = (const float*)d_in[8];
  float* out = (float*)d_out;

  char* ws = (char*)d_ws;
  unsigned char* vbf  = (unsigned char*)ws;                        // 8 MB (fp8 tiled)
  unsigned short* qbf = (unsigned short*)(ws + (16u << 20));       // 2 MB
  unsigned short* kbf = (unsigned short*)(ws + (18u << 20));       // 2 MB
  unsigned short* wqb = (unsigned short*)(ws + (20u << 20));       // 16 KB
  unsigned short* wkb = wqb + 8192;                                // 16 KB
  unsigned short* wvb = wkb + 8192;                                // 128 KB
  float* ssq = (float*)(wvb + 65536);                              // 2 KB

  prep_kernel<<<dim3(288), dim3(256), 0, stream>>>(Wq, Wk, Wv, wqb, wkb, wvb, ssq);
  qkv_kernel<<<dim3(512), dim3(512), 0, stream>>>(x, wqb, wkb, wvb, bq, bk, bv, qbf, kbf, vbf, ssq);
  attn_kernel<<<dim3(512), dim3(256), 0, stream>>>(qbf, kbf, vbf, ssq, temp, x, gam, out);
}

// Round 18
// 158.674 us; speedup vs baseline: 1.2076x; 1.0000x over previous
//
#include <hip/hip_runtime.h>
#include <hip/hip_bf16.h>
#include <math.h>

typedef __attribute__((ext_vector_type(8))) short short8;
typedef __attribute__((ext_vector_type(4))) float floatx4;
typedef __attribute__((ext_vector_type(16))) float floatx16;

#define B_ 8
#define C_ 256
#define N_ 4096
#define LOG2E 1.4426950408889634f
#define XSTRIDE 548   // qkv LDS row stride bytes (137 dw; 137%32=9 -> <=2-way banks r/w)

static __device__ __forceinline__ unsigned short f2bf(float f) {
  union { float f; unsigned int u; } v; v.f = f;
  unsigned int u = v.u;
  u += 0x7FFFu + ((u >> 16) & 1u);   // RNE
  return (unsigned short)(u >> 16);
}
static __device__ __forceinline__ float bf2f(unsigned short h) {
  union { unsigned int u; float f; } v; v.u = ((unsigned int)h) << 16; return v.f;
}
// truncation pack of two positive f32 -> bf16x2 in ONE v_perm_b32 (lo = a, hi = b)
static __device__ __forceinline__ unsigned int pk2(float a, float b) {
  return __builtin_amdgcn_perm(__float_as_uint(b), __float_as_uint(a), 0x07060302u);
}

// ---------------- kernel 0: weight convert + ssq zero ----------------
__global__ void prep_kernel(const float* __restrict__ Wq, const float* __restrict__ Wk,
                            const float* __restrict__ Wv,
                            unsigned short* __restrict__ wqb, unsigned short* __restrict__ wkb,
                            unsigned short* __restrict__ wvb, float* __restrict__ ssq) {
  int t = blockIdx.x * 256 + threadIdx.x;
  if (t < 512) ssq[t] = 0.0f;
  if (t < 8192) { wqb[t] = f2bf(Wq[t]); wkb[t] = f2bf(Wk[t]); }
  int tv = t - 8192;
  if (tv >= 0 && tv < 65536) wvb[tv] = f2bf(Wv[tv]);
}

// ---------------- kernel 1: QKV GEMM, 8-wave pipelined single-pass (r17) ----------------
__launch_bounds__(512, 4)
__global__ void qkv_kernel(const float* __restrict__ x,
                           const unsigned short* __restrict__ wqb,
                           const unsigned short* __restrict__ wkb,
                           const unsigned short* __restrict__ wvb,
                           const float* __restrict__ bq, const float* __restrict__ bk,
                           const float* __restrict__ bv,
                           unsigned short* __restrict__ qbf, unsigned short* __restrict__ kbf,
                           unsigned char* __restrict__ vbf, float* __restrict__ ssq) {
  __shared__ __align__(16) char Xt[64 * XSTRIDE];   // [64 n][256 c bf16 + pad]
  int b = blockIdx.x & 7;
  int nblk = blockIdx.x >> 3;
  int tid = threadIdx.x;
  int w = tid >> 6, lane = tid & 63;
  int r = lane & 15, g = lane >> 4;
  int nh = w & 3, ch = w >> 2;
  int n0 = nblk * 64;

  // ---- stage x tile: [c][n] fp32 -> [n][c] bf16 (transpose via regs), coalesced ----
  {
    int q = tid & 15, cpw = tid >> 4;               // q: float4 col, cpw: c-pair group
    const float* xb = x + ((size_t)b << 20) + n0 + q * 4;
    #pragma unroll
    for (int p = 0; p < 4; ++p) {
      int cp = p * 32 + cpw;                        // c-pair: c = 2cp, 2cp+1
      const float* s0 = xb + ((size_t)(2 * cp) << 12);
      float4 a  = *(const float4*)s0;
      float4 bb = *(const float4*)(s0 + 4096);
      char* dst = Xt + cp * 4;
      *(unsigned int*)(dst + (q * 4 + 0) * XSTRIDE) = pk2(a.x, bb.x);
      *(unsigned int*)(dst + (q * 4 + 1) * XSTRIDE) = pk2(a.y, bb.y);
      *(unsigned int*)(dst + (q * 4 + 2) * XSTRIDE) = pk2(a.z, bb.z);
      *(unsigned int*)(dst + (q * 4 + 3) * XSTRIDE) = pk2(a.w, bb.w);
    }
  }
  __syncthreads();

  // ---- x fragments: col n = n0 + nh*16 + r, k = ks*32 + g*8 + j ----
  short8 xf[8];
  #pragma unroll
  for (int ks = 0; ks < 8; ++ks) {
    const char* src = Xt + (nh * 16 + r) * XSTRIDE + (ks * 32 + g * 8) * 2;
    union { unsigned int u[4]; short8 s8; } t;
    t.u[0] = *(const unsigned int*)(src);
    t.u[1] = *(const unsigned int*)(src + 4);
    t.u[2] = *(const unsigned int*)(src + 8);
    t.u[3] = *(const unsigned int*)(src + 12);
    xf[ks] = t.s8;
  }
  int nw = n0 + nh * 16;
  floatx4 zero = {0.f, 0.f, 0.f, 0.f};
  unsigned char* vt = vbf + (size_t)b * C_ * N_;
  const unsigned short* wqk = ch ? wkb : wqb;
  const float* bias = ch ? bk : bq;
  unsigned short* qkdst = ch ? kbf : qbf;
  int sbase = ch ? 256 : 0;

  const unsigned short* vwb = wvb + (size_t)(ch * 128 + r) * 256 + g * 8;
  const unsigned short* qwb = wqk + (size_t)r * 256 + g * 8;

  short8 wf[2][4];
  #pragma unroll
  for (int j = 0; j < 4; ++j) wf[0][j] = *(const short8*)(vwb + j * 32);

  // per-lane V store base (n fixed): fp8 tiled layout
  int n = nw + r;
  size_t vsb = (size_t)(n >> 5) * 8192 + ((n >> 3) & 1) * 16 + ((n >> 4) & 1) * 8 + (n & 7);

  #pragma unroll
  for (int t = 0; t < 10; ++t) {
    const unsigned short* curb = (t < 8) ? (vwb + t * 4096) : (qwb + (t - 8) * 4096);
    const unsigned short* nxtb = (t < 7) ? (vwb + (t + 1) * 4096)
                                         : ((t < 9) ? (qwb + (t - 7) * 4096) : curb);
    floatx4 acc = zero;
    #pragma unroll
    for (int j = 0; j < 4; ++j) wf[1][j] = *(const short8*)(curb + (4 + j) * 32);
    #pragma unroll
    for (int j = 0; j < 4; ++j)
      acc = __builtin_amdgcn_mfma_f32_16x16x32_bf16(wf[0][j], xf[j], acc, 0, 0, 0);
    #pragma unroll
    for (int j = 0; j < 4; ++j) wf[0][j] = *(const short8*)(nxtb + j * 32);
    #pragma unroll
    for (int j = 0; j < 4; ++j)
      acc = __builtin_amdgcn_mfma_f32_16x16x32_bf16(wf[1][j], xf[4 + j], acc, 0, 0, 0);

    if (t < 8) {                                    // V tile: fp8 tiled-layout stores
      int otile = ch * 8 + t;
      #pragma unroll
      for (int rr = 0; rr < 4; ++rr) {
        int oc = otile * 16 + g * 4 + rr;
        float val = acc[rr] + bv[oc];
        int pk8 = __builtin_amdgcn_cvt_pk_fp8_f32(val, val, 0, false);
        vt[vsb + (size_t)oc * 32] = (unsigned char)(pk8 & 0xFF);
      }
    } else {                                        // Q (ch=0) / K (ch=1) tile
      #pragma unroll
      for (int rr = 0; rr < 4; ++rr) {
        int oc = (t - 8) * 16 + g * 4 + rr;
        float val = acc[rr] + bias[oc];
        qkdst[(size_t)(b * N_ + nw + r) * 32 + oc] = f2bf(val);
        float s = val * val;
        s += __shfl_xor(s, 1);
        s += __shfl_xor(s, 2);
        s += __shfl_xor(s, 4);
        s += __shfl_xor(s, 8);
        if (r == 0) atomicAdd(&ssq[sbase + b * 32 + oc], s);
      }
    }
  }
}

// ---------------- kernel 2: barrier-free attention, fp8 V/P, ones-MFMA L, depth-2 prefetch ----------------
// r17 thin structure + (a) denominator L computed by an extra fp8 MFMA with A = fp8(1.0)
// broadcast (reuses the PV B-operand; kills the 15-add tree + end shfl), (b) quad-buffered
// K/V with 2-tile prefetch distance (covers L2-miss bursts; VGPR ~180 within (256,2)).
__launch_bounds__(256, 2)
__global__ void attn_kernel(const unsigned short* __restrict__ qbf,
                            const unsigned short* __restrict__ kbf,
                            const unsigned char* __restrict__ vbf,
                            const float* __restrict__ ssq, const float* __restrict__ temp,
                            const float* __restrict__ x, const float* __restrict__ gamma,
                            float* __restrict__ out) {
  int b = blockIdx.x & 7, mblk = blockIdx.x >> 3;       // mblk in [0,64)
  int tid = threadIdx.x;
  int w = tid >> 6, lane = tid & 63, c = lane & 31, h = lane >> 5;
  int ms = w & 1, cvh = w >> 1;                         // 4 waves: ms(2) x cvh(2)
  const unsigned short* qb = qbf + (size_t)b * N_ * 32;
  const unsigned short* kb = kbf + (size_t)b * N_ * 32;
  const unsigned char* vt = vbf + (size_t)b * C_ * N_;
  int mrow = mblk * 64 + ms * 32 + c;                   // this lane's global m (column)
  int tdiag = mblk * 2 + ms;

  // ---- Q fragments with folded per-channel scale: invt*log2e/(||q_c||*||k_c||) ----
  float invt = LOG2E / (temp[0] + 1e-6f);
  short8 q0r = *(const short8*)&qb[mrow * 32 + h * 8];
  short8 q1r = *(const short8*)&qb[mrow * 32 + 16 + h * 8];
  short8 qf0, qf1;
  #pragma unroll
  for (int j = 0; j < 8; ++j) {
    int ch0 = h * 8 + j, ch1 = 16 + h * 8 + j;
    float s0 = invt * rsqrtf(fmaxf(ssq[b * 32 + ch0] * ssq[256 + b * 32 + ch0], 1e-24f));
    float s1 = invt * rsqrtf(fmaxf(ssq[b * 32 + ch1] * ssq[256 + b * 32 + ch1], 1e-24f));
    ((unsigned short*)&qf0)[j] = f2bf(bf2f(((const unsigned short*)&q0r)[j]) * s0);
    ((unsigned short*)&qf1)[j] = f2bf(bf2f(((const unsigned short*)&q1r)[j]) * s1);
  }

  // K fragment pointer: row n = t*32 + c, channels h*8 / 16+h*8; +1024 elems/tile
  const unsigned short* kp = kb + (size_t)c * 32 + h * 8;
  // V fragment pointer (fp8 tiled): 16B at cv*32 + h*16; +8192 B/tile; cvt imm cvt*1024
  const unsigned char* vp = vt + (size_t)(cvh * 128 + c) * 32 + h * 16;

  floatx16 minit;                                        // C-init = -2*log2e (softmax shift)
  #pragma unroll
  for (int i = 0; i < 16; ++i) minit[i] = -2.0f * LOG2E;
  floatx16 zero16 = {0,0,0,0,0,0,0,0,0,0,0,0,0,0,0,0};
  floatx16 acc[4] = {zero16, zero16, zero16, zero16};    // [cvt] D[cv 32][m 32]
  floatx16 accL = zero16;                                // ones-MFMA denominator
  const long ones8 = 0x3838383838383838L;                // 8x fp8 e4m3 1.0

  short8 kf[4][2];
  short8 af[4][4];

  auto issue = [&](int t, short8 (&kfN)[2], short8 (&afN)[4]) {
    if (t < 128) {
      kfN[0] = *(const short8*)kp;
      kfN[1] = *(const short8*)(kp + 16);
      kp += 1024;
      #pragma unroll
      for (int cvt = 0; cvt < 4; ++cvt)
        afN[cvt] = *(const short8*)(vp + cvt * 1024);
      vp += 8192;
    }
  };
  auto compute = [&](int t, short8 (&kfC)[2], short8 (&afC)[4]) {
    floatx16 s = __builtin_amdgcn_mfma_f32_32x32x16_bf16(kfC[0], qf0, minit, 0, 0, 0);
    s = __builtin_amdgcn_mfma_f32_32x32x16_bf16(kfC[1], qf1, s, 0, 0, 0);
    if (t == tdiag && ((c >> 2) & 1) == h)              // +I where global n == m
      s[(c & 3) | ((c >> 3) << 2)] += LOG2E;
    float p[16];
    #pragma unroll
    for (int i = 0; i < 16; ++i) p[i] = __builtin_amdgcn_exp2f(s[i]);
    #pragma unroll
    for (int t16 = 0; t16 < 2; ++t16) {
      int d0 = __builtin_amdgcn_cvt_pk_fp8_f32(p[8*t16+0], p[8*t16+1], 0, false);
      d0 = __builtin_amdgcn_cvt_pk_fp8_f32(p[8*t16+2], p[8*t16+3], d0, true);
      int d1 = __builtin_amdgcn_cvt_pk_fp8_f32(p[8*t16+4], p[8*t16+5], 0, false);
      d1 = __builtin_amdgcn_cvt_pk_fp8_f32(p[8*t16+6], p[8*t16+7], d1, true);
      // swap(vdst=d1, vsrc=d0): lo lanes d1 <- partner d0; hi lanes d0 <- partner d1
      asm volatile("v_permlane32_swap_b32 %0, %1" : "+v"(d1), "+v"(d0));
      long bl = (long)(((unsigned long long)(unsigned)d1 << 32) | (unsigned)d0);
      accL = __builtin_amdgcn_mfma_f32_32x32x16_fp8_fp8(ones8, bl, accL, 0, 0, 0);
      #pragma unroll
      for (int cvt = 0; cvt < 4; ++cvt) {
        union { short8 s8; long l[2]; } u; u.s8 = afC[cvt];
        acc[cvt] = __builtin_amdgcn_mfma_f32_32x32x16_fp8_fp8(u.l[t16], bl, acc[cvt], 0, 0, 0);
      }
    }
  };

  // ---- prologue: fill bufs 0,1 (prefetch distance 2) ----
  issue(0, kf[0], af[0]);
  issue(1, kf[1], af[1]);

  #pragma unroll 1
  for (int t = 0; t < 128; t += 4) {
    issue(t + 2, kf[2], af[2]);  compute(t + 0, kf[0], af[0]);
    issue(t + 3, kf[3], af[3]);  compute(t + 1, kf[1], af[1]);
    issue(t + 4, kf[0], af[0]);  compute(t + 2, kf[2], af[2]);
    issue(t + 5, kf[1], af[1]);  compute(t + 3, kf[3], af[3]);
  }

  // denominator directly from ones-MFMA (all acc rows equal; sums both k-halves)
  float linv = 1.0f / accL[0];
  float gam = gamma[0];
  #pragma unroll
  for (int cvt = 0; cvt < 4; ++cvt)
    #pragma unroll
    for (int i = 0; i < 16; ++i) {
      int cv = cvh * 128 + cvt * 32 + (i & 3) + 8 * (i >> 2) + 4 * h;
      size_t idx = ((size_t)(b * C_ + cv) << 12) + mrow;
      out[idx] = gam * acc[cvt][i] * linv + x[idx];
    }
}

extern "C" void kernel_launch(void* const* d_in, const int* in_sizes, int n_in,
                              void* d_out, int out_size, void* d_ws, size_t ws_size,
                              hipStream_t stream) {
  (void)in_sizes; (void)n_in; (void)out_size; (void)ws_size;
  const float* x    = (const float*)d_in[0];
  const float* Wq   = (const float*)d_in[1];
  const float* bq   = (const float*)d_in[2];
  const float* Wk   = (const float*)d_in[3];
  const float* bk   = (const float*)d_in[4];
  const float* Wv   = (const float*)d_in[5];
  const float* bv   = (const float*)d_in[6];
  const float* gam  = (const float*)d_in[7];
  const float* temp = (const float*)d_in[8];
  float* out = (float*)d_out;

  char* ws = (char*)d_ws;
  unsigned char* vbf  = (unsigned char*)ws;                        // 8 MB (fp8 tiled)
  unsigned short* qbf = (unsigned short*)(ws + (16u << 20));       // 2 MB
  unsigned short* kbf = (unsigned short*)(ws + (18u << 20));       // 2 MB
  unsigned short* wqb = (unsigned short*)(ws + (20u << 20));       // 16 KB
  unsigned short* wkb = wqb + 8192;                                // 16 KB
  unsigned short* wvb = wkb + 8192;                                // 128 KB
  float* ssq = (float*)(wvb + 65536);                              // 2 KB

  prep_kernel<<<dim3(288), dim3(256), 0, stream>>>(Wq, Wk, Wv, wqb, wkb, wvb, ssq);
  qkv_kernel<<<dim3(512), dim3(512), 0, stream>>>(x, wqb, wkb, wvb, bq, bk, bv, qbf, kbf, vbf, ssq);
  attn_kernel<<<dim3(512), dim3(256), 0, stream>>>(qbf, kbf, vbf, ssq, temp, x, gam, out);
}